// Round 1
// baseline (21725.735 us; speedup 1.0000x reference)
//
#include <hip/hip_runtime.h>
#include <cstdint>
#include <cstddef>

// ---------------------------------------------------------------------------
// MaskedContextEncoder: B=32 IMG=512 P=16 CIN=4 D=256 DEPTH=4 H=8 FF=2048
// N=1024 patches, L=512 selected (masked) per batch, DH=32.
// Round 1: correctness-first fp32 pipeline. MFMA comes later.
// ---------------------------------------------------------------------------

#define Bq 32
#define Dm 256
#define Lq 512
#define Nn 1024
#define Hh 8
#define DHh 32
#define FFq 2048
#define Mtok (Bq * Lq)   // 16384 rows

static __device__ __forceinline__ unsigned short f2bf(float f) {
    unsigned int u = __float_as_uint(f);
    unsigned int r = (u + 0x7FFFu + ((u >> 16) & 1u)) >> 16;
    return (unsigned short)r;
}
static __device__ __forceinline__ float bf2f(unsigned short h) {
    return __uint_as_float(((unsigned int)h) << 16);
}

// --------------------------- order (compaction) ----------------------------
// pmask[b,n] = mask[b, 0, (n>>5)*16, (n&31)*16]; sel = pmask < 0.5
// order[b,l] = indices of selected patches, ascending (stable compaction).
__global__ __launch_bounds__(1024) void k_order(const float* __restrict__ mask,
                                                int* __restrict__ order) {
    const int b = blockIdx.x;
    const int n = threadIdx.x;                       // 0..1023
    const float v = mask[(size_t)b * 262144 + (size_t)(n >> 5) * 8192 + (n & 31) * 16];
    const bool sel = v < 0.5f;
    const unsigned long long ball = __ballot(sel);
    const int wave = n >> 6, lane = n & 63;
    __shared__ int wsum[16];
    __shared__ int wpre[16];
    if (lane == 0) wsum[wave] = __popcll(ball);
    __syncthreads();
    if (n == 0) {
        int s = 0;
        for (int i = 0; i < 16; ++i) { wpre[i] = s; s += wsum[i]; }
    }
    __syncthreads();
    const int rank = wpre[wave] + __popcll(ball & ((1ull << lane) - 1ull));
    if (sel) order[b * Lq + rank] = n;
}

// ------------------------------ patch embed --------------------------------
// h[m, d] = sum_{k<768} patch[m][k] * conv_w[d*1024 + k] + conv_b[d] + pos[n,d]
// (mask channel contributes 0 on selected patches -> skip cin=3 entirely)
__global__ __launch_bounds__(256) void k_embed(const float* __restrict__ image,
                                               const int* __restrict__ order,
                                               const float* __restrict__ conv_w,
                                               const float* __restrict__ conv_b,
                                               const float* __restrict__ pos,
                                               float* __restrict__ Hout) {
    __shared__ float patch[16][768];
    __shared__ int pn[16];
    const int tid = threadIdx.x;
    const int tok0 = blockIdx.x * 16;
    if (tid < 16) pn[tid] = order[tok0 + tid];
    __syncthreads();
    // stage 16 patches x 3ch x 16x16 (coalesced 16-float rows)
    for (int iter = 0; iter < 48; ++iter) {
        const int t = iter / 3, c = iter % 3;
        const int n = pn[t];
        const int b = (tok0 + t) >> 9;
        const int pi = n >> 5, pj = n & 31;
        const int rr = tid >> 4, col = tid & 15;
        patch[t][c * 256 + rr * 16 + col] =
            image[(((size_t)b * 3 + c) * 512 + pi * 16 + rr) * 512 + pj * 16 + col];
    }
    __syncthreads();
    const int d = tid;
    float acc[16];
#pragma unroll
    for (int t = 0; t < 16; ++t) acc[t] = 0.f;
    for (int k4 = 0; k4 < 768; k4 += 4) {
        const float4 w4 = *(const float4*)&conv_w[(size_t)d * 1024 + k4];
#pragma unroll
        for (int t = 0; t < 16; ++t) {
            const float4 p4 = *(const float4*)&patch[t][k4];
            acc[t] += w4.x * p4.x + w4.y * p4.y + w4.z * p4.z + w4.w * p4.w;
        }
    }
    const float cb = conv_b[d];
#pragma unroll
    for (int t = 0; t < 16; ++t) {
        Hout[(size_t)(tok0 + t) * Dm + d] = acc[t] + cb + pos[(size_t)pn[t] * Dm + d];
    }
}

// ------------------------------- fp32 GEMM ---------------------------------
// C[M,N] = A[M,K] @ W[K,N] + bias[N] (+ R[M,N]) (, ReLU). 64x64 tile, 256 thr.
template <bool RELU, bool RES>
__global__ __launch_bounds__(256) void k_gemm(const float* __restrict__ A,
                                              const float* __restrict__ W,
                                              const float* __restrict__ bias,
                                              const float* __restrict__ R,
                                              float* __restrict__ C,
                                              int M, int N, int K) {
    __shared__ float AsT[16][68];   // [k][m], padded
    __shared__ float Ws[16][68];    // [k][n], padded
    const int tid = threadIdx.x;
    const int tx = tid & 15, ty = tid >> 4;
    const int n0 = blockIdx.x * 64, m0 = blockIdx.y * 64;
    float acc[4][4];
#pragma unroll
    for (int i = 0; i < 4; ++i)
#pragma unroll
        for (int j = 0; j < 4; ++j) acc[i][j] = 0.f;

    const int arow = tid >> 2;            // 0..63
    const int ak = (tid & 3) * 4;         // 0,4,8,12
    const int wr = tid >> 4;              // 0..15
    const int wc = (tid & 15) * 4;        // 0..60

    for (int k0 = 0; k0 < K; k0 += 16) {
        const float4 a4 = *(const float4*)&A[(size_t)(m0 + arow) * K + k0 + ak];
        const float4 w4 = *(const float4*)&W[(size_t)(k0 + wr) * N + n0 + wc];
        __syncthreads();
        AsT[ak + 0][arow] = a4.x;
        AsT[ak + 1][arow] = a4.y;
        AsT[ak + 2][arow] = a4.z;
        AsT[ak + 3][arow] = a4.w;
        *(float4*)&Ws[wr][wc] = w4;
        __syncthreads();
#pragma unroll
        for (int kk = 0; kk < 16; ++kk) {
            const float4 av = *(const float4*)&AsT[kk][ty * 4];
            const float4 wv = *(const float4*)&Ws[kk][tx * 4];
            const float a_[4] = {av.x, av.y, av.z, av.w};
            const float w_[4] = {wv.x, wv.y, wv.z, wv.w};
#pragma unroll
            for (int i = 0; i < 4; ++i)
#pragma unroll
                for (int j = 0; j < 4; ++j) acc[i][j] += a_[i] * w_[j];
        }
    }
    const float4 b4 = *(const float4*)&bias[n0 + tx * 4];
    const float bb[4] = {b4.x, b4.y, b4.z, b4.w};
#pragma unroll
    for (int i = 0; i < 4; ++i) {
        const int m = m0 + ty * 4 + i;
        float v[4];
#pragma unroll
        for (int j = 0; j < 4; ++j) v[j] = acc[i][j] + bb[j];
        if constexpr (RES) {
            const float4 r4 = *(const float4*)&R[(size_t)m * N + n0 + tx * 4];
            v[0] += r4.x; v[1] += r4.y; v[2] += r4.z; v[3] += r4.w;
        }
        if constexpr (RELU) {
#pragma unroll
            for (int j = 0; j < 4; ++j) v[j] = fmaxf(v[j], 0.f);
        }
        float4 o4 = {v[0], v[1], v[2], v[3]};
        *(float4*)&C[(size_t)m * N + n0 + tx * 4] = o4;
    }
}

// ------------------------------- layernorm ---------------------------------
__global__ __launch_bounds__(256) void k_ln(const float* __restrict__ X,
                                            float* __restrict__ Y,
                                            const float* __restrict__ s,
                                            const float* __restrict__ b) {
    const int row = blockIdx.x * 4 + (threadIdx.x >> 6);
    const int lane = threadIdx.x & 63;
    const float4 v = *(const float4*)&X[(size_t)row * Dm + lane * 4];
    float sum = v.x + v.y + v.z + v.w;
#pragma unroll
    for (int off = 32; off; off >>= 1) sum += __shfl_xor(sum, off);
    const float mean = sum * (1.f / 256.f);
    const float dx[4] = {v.x - mean, v.y - mean, v.z - mean, v.w - mean};
    float vv = dx[0] * dx[0] + dx[1] * dx[1] + dx[2] * dx[2] + dx[3] * dx[3];
#pragma unroll
    for (int off = 32; off; off >>= 1) vv += __shfl_xor(vv, off);
    const float inv = rsqrtf(vv * (1.f / 256.f) + 1e-5f);
    const float4 sv = *(const float4*)&s[lane * 4];
    const float4 bv = *(const float4*)&b[lane * 4];
    float4 o;
    o.x = dx[0] * inv * sv.x + bv.x;
    o.y = dx[1] * inv * sv.y + bv.y;
    o.z = dx[2] * inv * sv.z + bv.z;
    o.w = dx[3] * inv * sv.w + bv.w;
    *(float4*)&Y[(size_t)row * Dm + lane * 4] = o;
}

// ------------------------------- attention ---------------------------------
// One block per (b,h). K,V staged in LDS as bf16 with XOR-swizzled 4-elem
// groups (64 KiB exactly). One wave per q-row, lane j covers k = {j*64+lane}.
__global__ __launch_bounds__(1024) void k_attn(const float* __restrict__ QKV,
                                               float* __restrict__ O) {
    __shared__ unsigned short Ks[Lq * DHh];
    __shared__ unsigned short Vs[Lq * DHh];
    const int bh = blockIdx.x;
    const int b = bh >> 3, h = bh & 7;
    const int tid = threadIdx.x;

    for (int i = tid; i < Lq * DHh; i += 1024) {
        const int k = i >> 5, d = i & 31;
        const size_t base = (size_t)(b * Lq + k) * 768 + h * DHh + d;
        const int gp = (d >> 2) ^ ((k >> 1) & 7);
        const int posi = k * 32 + gp * 4 + (d & 3);
        Ks[posi] = f2bf(QKV[base + 256]);
        Vs[posi] = f2bf(QKV[base + 512]);
    }
    __syncthreads();

    const int wave = tid >> 6, lane = tid & 63;
    const float scale = 0.17677669529663687f;   // 1/sqrt(32)

    for (int r = 0; r < 32; ++r) {
        const int q_idx = wave * 32 + r;
        const float* qp = &QKV[(size_t)(b * Lq + q_idx) * 768 + h * DHh];
        float q[32];
#pragma unroll
        for (int c = 0; c < 8; ++c) {
            const float4 q4 = *(const float4*)&qp[c * 4];
            q[c * 4 + 0] = q4.x; q[c * 4 + 1] = q4.y;
            q[c * 4 + 2] = q4.z; q[c * 4 + 3] = q4.w;
        }
        float sc[8];
#pragma unroll
        for (int j = 0; j < 8; ++j) {
            const int k = j * 64 + lane;
            const int swz = (k >> 1) & 7;
            float dot = 0.f;
#pragma unroll
            for (int g = 0; g < 8; ++g) {
                const int gp = g ^ swz;
                const uint2 kk_ = *(const uint2*)&Ks[k * 32 + gp * 4];
                dot += q[g * 4 + 0] * bf2f((unsigned short)(kk_.x & 0xffff));
                dot += q[g * 4 + 1] * bf2f((unsigned short)(kk_.x >> 16));
                dot += q[g * 4 + 2] * bf2f((unsigned short)(kk_.y & 0xffff));
                dot += q[g * 4 + 3] * bf2f((unsigned short)(kk_.y >> 16));
            }
            sc[j] = dot * scale;
        }
        // softmax over 512 (8 per lane x 64 lanes)
        float mx = sc[0];
#pragma unroll
        for (int j = 1; j < 8; ++j) mx = fmaxf(mx, sc[j]);
#pragma unroll
        for (int off = 32; off; off >>= 1) mx = fmaxf(mx, __shfl_xor(mx, off));
        float sum = 0.f;
#pragma unroll
        for (int j = 0; j < 8; ++j) { sc[j] = __expf(sc[j] - mx); sum += sc[j]; }
#pragma unroll
        for (int off = 32; off; off >>= 1) sum += __shfl_xor(sum, off);
        const float inv = 1.f / sum;

        float oacc[32];
#pragma unroll
        for (int d = 0; d < 32; ++d) oacc[d] = 0.f;
#pragma unroll
        for (int j = 0; j < 8; ++j) {
            const int k = j * 64 + lane;
            const float a = sc[j] * inv;
            const int swz = (k >> 1) & 7;
#pragma unroll
            for (int g = 0; g < 8; ++g) {
                const int gp = g ^ swz;
                const uint2 vv = *(const uint2*)&Vs[k * 32 + gp * 4];
                oacc[g * 4 + 0] += a * bf2f((unsigned short)(vv.x & 0xffff));
                oacc[g * 4 + 1] += a * bf2f((unsigned short)(vv.x >> 16));
                oacc[g * 4 + 2] += a * bf2f((unsigned short)(vv.y & 0xffff));
                oacc[g * 4 + 3] += a * bf2f((unsigned short)(vv.y >> 16));
            }
        }
#pragma unroll
        for (int off = 32; off; off >>= 1)
#pragma unroll
            for (int d = 0; d < 32; ++d) oacc[d] += __shfl_xor(oacc[d], off);
        if (lane < 8) {
            float4 o4 = {oacc[lane * 4 + 0], oacc[lane * 4 + 1],
                         oacc[lane * 4 + 2], oacc[lane * 4 + 3]};
            *(float4*)&O[(size_t)(b * Lq + q_idx) * Dm + h * DHh + lane * 4] = o4;
        }
    }
}

// ------------------------------- launcher ----------------------------------
extern "C" void kernel_launch(void* const* d_in, const int* in_sizes, int n_in,
                              void* d_out, int out_size, void* d_ws, size_t ws_size,
                              hipStream_t stream) {
    const float* image  = (const float*)d_in[0];
    const float* mask   = (const float*)d_in[1];
    const float* conv_w = (const float*)d_in[2];
    const float* conv_b = (const float*)d_in[3];
    const float* pos    = (const float*)d_in[4];
    const float* qkv_w  = (const float*)d_in[5];
    const float* qkv_b  = (const float*)d_in[6];
    const float* out_w  = (const float*)d_in[7];
    const float* out_b  = (const float*)d_in[8];
    const float* ln1_s  = (const float*)d_in[9];
    const float* ln1_b  = (const float*)d_in[10];
    const float* ff1_w  = (const float*)d_in[11];
    const float* ff1_b  = (const float*)d_in[12];
    const float* ff2_w  = (const float*)d_in[13];
    const float* ff2_b  = (const float*)d_in[14];
    const float* ln2_s  = (const float*)d_in[15];
    const float* ln2_b  = (const float*)d_in[16];
    float* out = (float*)d_out;

    // workspace layout (all 256B-aligned by construction)
    char* w = (char*)d_ws;
    int* order  = (int*)w;                 w += (size_t)Mtok * 4;           // 64 KB
    float* Hbuf = (float*)w;               w += (size_t)Mtok * Dm * 4;      // 16 MB
    float* QKV  = (float*)w;               w += (size_t)Mtok * 3 * Dm * 4;  // 50 MB
    float* Obuf = (float*)w;               w += (size_t)Mtok * Dm * 4;      // 16 MB
    float* Xbuf = (float*)w;               w += (size_t)Mtok * Dm * 4;      // 16 MB
    float* Fbuf = (float*)w;               /* 8192 x 2048 f32 = 67 MB */

    k_order<<<Bq, 1024, 0, stream>>>(mask, order);
    k_embed<<<Mtok / 16, 256, 0, stream>>>(image, order, conv_w, conv_b, pos, Hbuf);

    const int MC = 8192;   // ff M-chunk (bounds Fbuf)
    for (int i = 0; i < 4; ++i) {
        // qkv projection: [16384,256]@[256,768]
        k_gemm<false, false><<<dim3(768 / 64, Mtok / 64), 256, 0, stream>>>(
            Hbuf, qkv_w + (size_t)i * Dm * 3 * Dm, qkv_b + (size_t)i * 3 * Dm,
            nullptr, QKV, Mtok, 3 * Dm, Dm);
        // attention
        k_attn<<<Bq * Hh, 1024, 0, stream>>>(QKV, Obuf);
        // out projection + residual -> Xbuf
        k_gemm<false, true><<<dim3(Dm / 64, Mtok / 64), 256, 0, stream>>>(
            Obuf, out_w + (size_t)i * Dm * Dm, out_b + (size_t)i * Dm,
            Hbuf, Xbuf, Mtok, Dm, Dm);
        // ln1 -> Hbuf
        k_ln<<<Mtok / 4, 256, 0, stream>>>(Xbuf, Hbuf, ln1_s + i * Dm, ln1_b + i * Dm);
        // ff (chunked over M to bound F buffer)
        for (int c = 0; c < Mtok / MC; ++c) {
            const size_t moff = (size_t)c * MC;
            k_gemm<true, false><<<dim3(FFq / 64, MC / 64), 256, 0, stream>>>(
                Hbuf + moff * Dm, ff1_w + (size_t)i * Dm * FFq, ff1_b + (size_t)i * FFq,
                nullptr, Fbuf, MC, FFq, Dm);
            k_gemm<false, true><<<dim3(Dm / 64, MC / 64), 256, 0, stream>>>(
                Fbuf, ff2_w + (size_t)i * FFq * Dm, ff2_b + (size_t)i * Dm,
                Hbuf + moff * Dm, Xbuf + moff * Dm, MC, Dm, FFq);
        }
        // ln2 -> Hbuf (final layer writes d_out)
        float* dst = (i == 3) ? out : Hbuf;
        k_ln<<<Mtok / 4, 256, 0, stream>>>(Xbuf, dst, ln2_s + i * Dm, ln2_b + i * Dm);
    }
    (void)in_sizes; (void)n_in; (void)out_size; (void)ws_size;
}

// Round 2
// 13222.986 us; speedup vs baseline: 1.6430x; 1.6430x over previous
//
#include <hip/hip_runtime.h>
#include <cstdint>
#include <cstddef>

// ---------------------------------------------------------------------------
// MaskedContextEncoder: B=32 IMG=512 P=16 CIN=4 D=256 DEPTH=4 H=8 FF=2048
// N=1024 patches, L=512 selected per batch, DH=32.
// Round 2: spill-free LDS attention (R1 spilled q[32]+oacc[32] -> 7.6GB
// scratch traffic per dispatch). GEMMs unchanged (MFMA next round).
// ---------------------------------------------------------------------------

#define Bq 32
#define Dm 256
#define Lq 512
#define Nn 1024
#define Hh 8
#define DHh 32
#define FFq 2048
#define Mtok (Bq * Lq)   // 16384 rows

static __device__ __forceinline__ unsigned short f2bf(float f) {
    unsigned int u = __float_as_uint(f);
    unsigned int r = (u + 0x7FFFu + ((u >> 16) & 1u)) >> 16;
    return (unsigned short)r;
}
static __device__ __forceinline__ float bf2f(unsigned short h) {
    return __uint_as_float(((unsigned int)h) << 16);
}
static __device__ __forceinline__ unsigned int pkbf(float lo, float hi) {
    return (unsigned int)f2bf(lo) | ((unsigned int)f2bf(hi) << 16);
}
static __device__ __forceinline__ float blo(unsigned int u) {
    return __uint_as_float(u << 16);
}
static __device__ __forceinline__ float bhi(unsigned int u) {
    return __uint_as_float(u & 0xffff0000u);
}

// --------------------------- order (compaction) ----------------------------
__global__ __launch_bounds__(1024) void k_order(const float* __restrict__ mask,
                                                int* __restrict__ order) {
    const int b = blockIdx.x;
    const int n = threadIdx.x;                       // 0..1023
    const float v = mask[(size_t)b * 262144 + (size_t)(n >> 5) * 8192 + (n & 31) * 16];
    const bool sel = v < 0.5f;
    const unsigned long long ball = __ballot(sel);
    const int wave = n >> 6, lane = n & 63;
    __shared__ int wsum[16];
    __shared__ int wpre[16];
    if (lane == 0) wsum[wave] = __popcll(ball);
    __syncthreads();
    if (n == 0) {
        int s = 0;
        for (int i = 0; i < 16; ++i) { wpre[i] = s; s += wsum[i]; }
    }
    __syncthreads();
    const int rank = wpre[wave] + __popcll(ball & ((1ull << lane) - 1ull));
    if (sel) order[b * Lq + rank] = n;
}

// ------------------------------ patch embed --------------------------------
__global__ __launch_bounds__(256) void k_embed(const float* __restrict__ image,
                                               const int* __restrict__ order,
                                               const float* __restrict__ conv_w,
                                               const float* __restrict__ conv_b,
                                               const float* __restrict__ pos,
                                               float* __restrict__ Hout) {
    __shared__ float patch[16][768];
    __shared__ int pn[16];
    const int tid = threadIdx.x;
    const int tok0 = blockIdx.x * 16;
    if (tid < 16) pn[tid] = order[tok0 + tid];
    __syncthreads();
    for (int iter = 0; iter < 48; ++iter) {
        const int t = iter / 3, c = iter % 3;
        const int n = pn[t];
        const int b = (tok0 + t) >> 9;
        const int pi = n >> 5, pj = n & 31;
        const int rr = tid >> 4, col = tid & 15;
        patch[t][c * 256 + rr * 16 + col] =
            image[(((size_t)b * 3 + c) * 512 + pi * 16 + rr) * 512 + pj * 16 + col];
    }
    __syncthreads();
    const int d = tid;
    float acc[16];
#pragma unroll
    for (int t = 0; t < 16; ++t) acc[t] = 0.f;
    for (int k4 = 0; k4 < 768; k4 += 4) {
        const float4 w4 = *(const float4*)&conv_w[(size_t)d * 1024 + k4];
#pragma unroll
        for (int t = 0; t < 16; ++t) {
            const float4 p4 = *(const float4*)&patch[t][k4];
            acc[t] += w4.x * p4.x + w4.y * p4.y + w4.z * p4.z + w4.w * p4.w;
        }
    }
    const float cb = conv_b[d];
#pragma unroll
    for (int t = 0; t < 16; ++t) {
        Hout[(size_t)(tok0 + t) * Dm + d] = acc[t] + cb + pos[(size_t)pn[t] * Dm + d];
    }
}

// ------------------------------- fp32 GEMM ---------------------------------
template <bool RELU, bool RES>
__global__ __launch_bounds__(256) void k_gemm(const float* __restrict__ A,
                                              const float* __restrict__ W,
                                              const float* __restrict__ bias,
                                              const float* __restrict__ R,
                                              float* __restrict__ C,
                                              int M, int N, int K) {
    __shared__ float AsT[16][68];   // [k][m], padded
    __shared__ float Ws[16][68];    // [k][n], padded
    const int tid = threadIdx.x;
    const int tx = tid & 15, ty = tid >> 4;
    const int n0 = blockIdx.x * 64, m0 = blockIdx.y * 64;
    float acc[4][4];
#pragma unroll
    for (int i = 0; i < 4; ++i)
#pragma unroll
        for (int j = 0; j < 4; ++j) acc[i][j] = 0.f;

    const int arow = tid >> 2;            // 0..63
    const int ak = (tid & 3) * 4;         // 0,4,8,12
    const int wr = tid >> 4;              // 0..15
    const int wc = (tid & 15) * 4;        // 0..60

    for (int k0 = 0; k0 < K; k0 += 16) {
        const float4 a4 = *(const float4*)&A[(size_t)(m0 + arow) * K + k0 + ak];
        const float4 w4 = *(const float4*)&W[(size_t)(k0 + wr) * N + n0 + wc];
        __syncthreads();
        AsT[ak + 0][arow] = a4.x;
        AsT[ak + 1][arow] = a4.y;
        AsT[ak + 2][arow] = a4.z;
        AsT[ak + 3][arow] = a4.w;
        *(float4*)&Ws[wr][wc] = w4;
        __syncthreads();
#pragma unroll
        for (int kk = 0; kk < 16; ++kk) {
            const float4 av = *(const float4*)&AsT[kk][ty * 4];
            const float4 wv = *(const float4*)&Ws[kk][tx * 4];
            const float a_[4] = {av.x, av.y, av.z, av.w};
            const float w_[4] = {wv.x, wv.y, wv.z, wv.w};
#pragma unroll
            for (int i = 0; i < 4; ++i)
#pragma unroll
                for (int j = 0; j < 4; ++j) acc[i][j] += a_[i] * w_[j];
        }
    }
    const float4 b4 = *(const float4*)&bias[n0 + tx * 4];
    const float bb[4] = {b4.x, b4.y, b4.z, b4.w};
#pragma unroll
    for (int i = 0; i < 4; ++i) {
        const int m = m0 + ty * 4 + i;
        float v[4];
#pragma unroll
        for (int j = 0; j < 4; ++j) v[j] = acc[i][j] + bb[j];
        if constexpr (RES) {
            const float4 r4 = *(const float4*)&R[(size_t)m * N + n0 + tx * 4];
            v[0] += r4.x; v[1] += r4.y; v[2] += r4.z; v[3] += r4.w;
        }
        if constexpr (RELU) {
#pragma unroll
            for (int j = 0; j < 4; ++j) v[j] = fmaxf(v[j], 0.f);
        }
        float4 o4 = {v[0], v[1], v[2], v[3]};
        *(float4*)&C[(size_t)m * N + n0 + tx * 4] = o4;
    }
}

// ------------------------------- layernorm ---------------------------------
__global__ __launch_bounds__(256) void k_ln(const float* __restrict__ X,
                                            float* __restrict__ Y,
                                            const float* __restrict__ s,
                                            const float* __restrict__ b) {
    const int row = blockIdx.x * 4 + (threadIdx.x >> 6);
    const int lane = threadIdx.x & 63;
    const float4 v = *(const float4*)&X[(size_t)row * Dm + lane * 4];
    float sum = v.x + v.y + v.z + v.w;
#pragma unroll
    for (int off = 32; off; off >>= 1) sum += __shfl_xor(sum, off);
    const float mean = sum * (1.f / 256.f);
    const float dx[4] = {v.x - mean, v.y - mean, v.z - mean, v.w - mean};
    float vv = dx[0] * dx[0] + dx[1] * dx[1] + dx[2] * dx[2] + dx[3] * dx[3];
#pragma unroll
    for (int off = 32; off; off >>= 1) vv += __shfl_xor(vv, off);
    const float inv = rsqrtf(vv * (1.f / 256.f) + 1e-5f);
    const float4 sv = *(const float4*)&s[lane * 4];
    const float4 bv = *(const float4*)&b[lane * 4];
    float4 o;
    o.x = dx[0] * inv * sv.x + bv.x;
    o.y = dx[1] * inv * sv.y + bv.y;
    o.z = dx[2] * inv * sv.z + bv.z;
    o.w = dx[3] * inv * sv.w + bv.w;
    *(float4*)&Y[(size_t)row * Dm + lane * 4] = o;
}

// ------------------------------- attention ---------------------------------
// One block per (b,h), 1024 thr = 16 waves, each wave owns 32 q-rows.
// K staged as XOR-swizzled 16B granules (k-major), V as swizzled granules
// transposed (d-major), P routed through per-wave LDS row buffer.
// All LDS reads derived conflict-free; no per-lane arrays beyond q[32].
__global__ __launch_bounds__(1024, 4) void k_attn(const float* __restrict__ QKV,
                                                  float* __restrict__ O) {
    __shared__ uint4 KsG[2048];          // 32 KB: granule (k, gi): K[k][gi*8 .. +7]
    __shared__ uint4 VsG[2048];          // 32 KB: granule (r, jj): V[(r&1)*256 + jj*8 ..][r>>1]
    __shared__ float Pbuf[16][520];      // 33.3 KB: per-wave P row (half-offset 260)
    const int bh = blockIdx.x;
    const int b = bh >> 3, h = bh & 7;
    const int tid = threadIdx.x;

    // ---- stage K (coalesced 32B/thread chunks) ----
    for (int g = tid; g < 2048; g += 1024) {
        const int k = g >> 2, gi = g & 3;
        const size_t base = (size_t)(b * Lq + k) * 768 + 256 + h * DHh + gi * 8;
        const float4 x0 = *(const float4*)&QKV[base];
        const float4 x1 = *(const float4*)&QKV[base + 4];
        uint4 u;
        u.x = pkbf(x0.x, x0.y); u.y = pkbf(x0.z, x0.w);
        u.z = pkbf(x1.x, x1.y); u.w = pkbf(x1.z, x1.w);
        KsG[k * 4 + (gi ^ ((k >> 1) & 3))] = u;
    }
    // ---- stage V (coalesced loads, b16 swizzled scatter) ----
    unsigned short* Vs16 = (unsigned short*)VsG;
    for (int e = tid; e < Lq * DHh; e += 1024) {
        const int d = e & 31, k = e >> 5;
        const float val = QKV[(size_t)(b * Lq + k) * 768 + 512 + h * DHh + d];
        const int r = (d << 1) | (k >> 8);
        const int jj = (k & 255) >> 3;
        const int g16 = r * 32 + (jj ^ (r & 7));
        Vs16[g16 * 8 + (k & 7)] = f2bf(val);
    }
    __syncthreads();

    const int wave = tid >> 6, lane = tid & 63;
    const float scale = 0.17677669529663687f;   // 1/sqrt(32)
    const int swzk = (lane >> 1) & 3;           // k-swizzle sel (k&7 == lane&7 per j)
    const int swzr = lane & 7;                  // v-swizzle sel
    const int kh = lane & 1, dv = lane >> 1;    // phase-2 ownership

    for (int rr = 0; rr < 32; ++rr) {
        const int q_idx = wave * 32 + rr;
        const float* qp = &QKV[(size_t)(b * Lq + q_idx) * 768 + h * DHh];
        float q[32];
#pragma unroll
        for (int c = 0; c < 8; ++c) {
            const float4 q4 = *(const float4*)&qp[c * 4];
            q[c * 4 + 0] = q4.x; q[c * 4 + 1] = q4.y;
            q[c * 4 + 2] = q4.z; q[c * 4 + 3] = q4.w;
        }
        // --- phase 1: scores for k = j*64 + lane ---
        float p[8];
#pragma unroll
        for (int j = 0; j < 8; ++j) {
            const int k = j * 64 + lane;
            float dot = 0.f;
#pragma unroll
            for (int gi = 0; gi < 4; ++gi) {
                const uint4 gk = KsG[k * 4 + (gi ^ swzk)];
                dot += q[gi * 8 + 0] * blo(gk.x) + q[gi * 8 + 1] * bhi(gk.x);
                dot += q[gi * 8 + 2] * blo(gk.y) + q[gi * 8 + 3] * bhi(gk.y);
                dot += q[gi * 8 + 4] * blo(gk.z) + q[gi * 8 + 5] * bhi(gk.z);
                dot += q[gi * 8 + 6] * blo(gk.w) + q[gi * 8 + 7] * bhi(gk.w);
            }
            p[j] = dot * scale;
        }
        float mx = p[0];
#pragma unroll
        for (int j = 1; j < 8; ++j) mx = fmaxf(mx, p[j]);
#pragma unroll
        for (int off = 32; off; off >>= 1) mx = fmaxf(mx, __shfl_xor(mx, off));
        float sum = 0.f;
#pragma unroll
        for (int j = 0; j < 8; ++j) { p[j] = __expf(p[j] - mx); sum += p[j]; }
#pragma unroll
        for (int off = 32; off; off >>= 1) sum += __shfl_xor(sum, off);
        const float inv = 1.f / sum;
#pragma unroll
        for (int j = 0; j < 8; ++j) {
            const int k = j * 64 + lane;
            Pbuf[wave][(k >> 8) * 260 + (k & 255)] = p[j];
        }
        // --- phase 2: O[dv] partial over ks kh*256..+255 (wave-local, no barrier) ---
        float oacc = 0.f;
#pragma unroll
        for (int jj = 0; jj < 32; ++jj) {
            const uint4 vg = VsG[lane * 32 + (jj ^ swzr)];
            const float4 p0 = *(const float4*)&Pbuf[wave][kh * 260 + jj * 8];
            const float4 p1 = *(const float4*)&Pbuf[wave][kh * 260 + jj * 8 + 4];
            oacc += p0.x * blo(vg.x) + p0.y * bhi(vg.x);
            oacc += p0.z * blo(vg.y) + p0.w * bhi(vg.y);
            oacc += p1.x * blo(vg.z) + p1.y * bhi(vg.z);
            oacc += p1.z * blo(vg.w) + p1.w * bhi(vg.w);
        }
        oacc *= inv;
        oacc += __shfl_xor(oacc, 1);
        if (kh == 0) {
            O[(size_t)(b * Lq + q_idx) * Dm + h * DHh + dv] = oacc;
        }
    }
}

// ------------------------------- launcher ----------------------------------
extern "C" void kernel_launch(void* const* d_in, const int* in_sizes, int n_in,
                              void* d_out, int out_size, void* d_ws, size_t ws_size,
                              hipStream_t stream) {
    const float* image  = (const float*)d_in[0];
    const float* mask   = (const float*)d_in[1];
    const float* conv_w = (const float*)d_in[2];
    const float* conv_b = (const float*)d_in[3];
    const float* pos    = (const float*)d_in[4];
    const float* qkv_w  = (const float*)d_in[5];
    const float* qkv_b  = (const float*)d_in[6];
    const float* out_w  = (const float*)d_in[7];
    const float* out_b  = (const float*)d_in[8];
    const float* ln1_s  = (const float*)d_in[9];
    const float* ln1_b  = (const float*)d_in[10];
    const float* ff1_w  = (const float*)d_in[11];
    const float* ff1_b  = (const float*)d_in[12];
    const float* ff2_w  = (const float*)d_in[13];
    const float* ff2_b  = (const float*)d_in[14];
    const float* ln2_s  = (const float*)d_in[15];
    const float* ln2_b  = (const float*)d_in[16];
    float* out = (float*)d_out;

    char* w = (char*)d_ws;
    int* order  = (int*)w;                 w += (size_t)Mtok * 4;           // 64 KB
    float* Hbuf = (float*)w;               w += (size_t)Mtok * Dm * 4;      // 16 MB
    float* QKV  = (float*)w;               w += (size_t)Mtok * 3 * Dm * 4;  // 50 MB
    float* Obuf = (float*)w;               w += (size_t)Mtok * Dm * 4;      // 16 MB
    float* Xbuf = (float*)w;               w += (size_t)Mtok * Dm * 4;      // 16 MB
    float* Fbuf = (float*)w;               /* 8192 x 2048 f32 = 67 MB */

    k_order<<<Bq, 1024, 0, stream>>>(mask, order);
    k_embed<<<Mtok / 16, 256, 0, stream>>>(image, order, conv_w, conv_b, pos, Hbuf);

    const int MC = 8192;
    for (int i = 0; i < 4; ++i) {
        k_gemm<false, false><<<dim3(768 / 64, Mtok / 64), 256, 0, stream>>>(
            Hbuf, qkv_w + (size_t)i * Dm * 3 * Dm, qkv_b + (size_t)i * 3 * Dm,
            nullptr, QKV, Mtok, 3 * Dm, Dm);
        k_attn<<<Bq * Hh, 1024, 0, stream>>>(QKV, Obuf);
        k_gemm<false, true><<<dim3(Dm / 64, Mtok / 64), 256, 0, stream>>>(
            Obuf, out_w + (size_t)i * Dm * Dm, out_b + (size_t)i * Dm,
            Hbuf, Xbuf, Mtok, Dm, Dm);
        k_ln<<<Mtok / 4, 256, 0, stream>>>(Xbuf, Hbuf, ln1_s + i * Dm, ln1_b + i * Dm);
        for (int c = 0; c < Mtok / MC; ++c) {
            const size_t moff = (size_t)c * MC;
            k_gemm<true, false><<<dim3(FFq / 64, MC / 64), 256, 0, stream>>>(
                Hbuf + moff * Dm, ff1_w + (size_t)i * Dm * FFq, ff1_b + (size_t)i * FFq,
                nullptr, Fbuf, MC, FFq, Dm);
            k_gemm<false, true><<<dim3(Dm / 64, MC / 64), 256, 0, stream>>>(
                Fbuf, ff2_w + (size_t)i * FFq * Dm, ff2_b + (size_t)i * Dm,
                Hbuf + moff * Dm, Xbuf + moff * Dm, MC, Dm, FFq);
        }
        float* dst = (i == 3) ? out : Hbuf;
        k_ln<<<Mtok / 4, 256, 0, stream>>>(Xbuf, dst, ln2_s + i * Dm, ln2_b + i * Dm);
    }
    (void)in_sizes; (void)n_in; (void)out_size; (void)ws_size;
}

// Round 4
// 884.744 us; speedup vs baseline: 24.5560x; 14.9456x over previous
//
#include <hip/hip_runtime.h>
#include <cstdint>
#include <cstddef>

// ---------------------------------------------------------------------------
// MaskedContextEncoder: B=32 IMG=512 P=16 CIN=4 D=256 DEPTH=4 H=8 FF=2048
// Round 4: fix k_wprep store-width bug (R3 wrote only 8 of 16 converted
// shorts -> half of every weight's K entries were poison ~0 -> absmax 1.67).
// MFMA GEMMs + MFMA flash attention otherwise identical to R3.
// ---------------------------------------------------------------------------

#define Bq 32
#define Dm 256
#define Lq 512
#define Hh 8
#define FFq 2048
#define Mtok (Bq * Lq)   // 16384 rows

typedef __attribute__((ext_vector_type(8))) short  short8;
typedef __attribute__((ext_vector_type(4))) float  f32x4;
typedef __attribute__((ext_vector_type(4))) unsigned int u32x4;
typedef __attribute__((ext_vector_type(2))) unsigned int u32x2;

static __device__ __forceinline__ unsigned short f2bf(float f) {
    unsigned int u = __float_as_uint(f);
    unsigned int r = (u + 0x7FFFu + ((u >> 16) & 1u)) >> 16;
    return (unsigned short)r;
}

static __device__ __forceinline__ void gload_lds16(const void* g, void* l) {
    __builtin_amdgcn_global_load_lds(
        (const __attribute__((address_space(1))) unsigned int*)g,
        (__attribute__((address_space(3))) unsigned int*)l, 16, 0, 0);
}

// --------------------------- order (compaction) ----------------------------
__global__ __launch_bounds__(1024) void k_order(const float* __restrict__ mask,
                                                int* __restrict__ order) {
    const int b = blockIdx.x;
    const int n = threadIdx.x;
    const float v = mask[(size_t)b * 262144 + (size_t)(n >> 5) * 8192 + (n & 31) * 16];
    const bool sel = v < 0.5f;
    const unsigned long long ball = __ballot(sel);
    const int wave = n >> 6, lane = n & 63;
    __shared__ int wsum[16];
    __shared__ int wpre[16];
    if (lane == 0) wsum[wave] = __popcll(ball);
    __syncthreads();
    if (n == 0) {
        int s = 0;
        for (int i = 0; i < 16; ++i) { wpre[i] = s; s += wsum[i]; }
    }
    __syncthreads();
    const int rank = wpre[wave] + __popcll(ball & ((1ull << lane) - 1ull));
    if (sel) order[b * Lq + rank] = n;
}

// ------------------------------ patch embed --------------------------------
__global__ __launch_bounds__(256) void k_embed(const float* __restrict__ image,
                                               const int* __restrict__ order,
                                               const float* __restrict__ conv_w,
                                               const float* __restrict__ conv_b,
                                               const float* __restrict__ pos,
                                               float* __restrict__ H32,
                                               unsigned short* __restrict__ H16) {
    __shared__ float patch[16][768];
    __shared__ int pn[16];
    const int tid = threadIdx.x;
    const int tok0 = blockIdx.x * 16;
    if (tid < 16) pn[tid] = order[tok0 + tid];
    __syncthreads();
    for (int iter = 0; iter < 48; ++iter) {
        const int t = iter / 3, c = iter % 3;
        const int n = pn[t];
        const int b = (tok0 + t) >> 9;
        const int pi = n >> 5, pj = n & 31;
        const int rr = tid >> 4, col = tid & 15;
        patch[t][c * 256 + rr * 16 + col] =
            image[(((size_t)b * 3 + c) * 512 + pi * 16 + rr) * 512 + pj * 16 + col];
    }
    __syncthreads();
    const int d = tid;
    float acc[16];
#pragma unroll
    for (int t = 0; t < 16; ++t) acc[t] = 0.f;
    for (int k4 = 0; k4 < 768; k4 += 4) {
        const float4 w4 = *(const float4*)&conv_w[(size_t)d * 1024 + k4];
#pragma unroll
        for (int t = 0; t < 16; ++t) {
            const float4 p4 = *(const float4*)&patch[t][k4];
            acc[t] += w4.x * p4.x + w4.y * p4.y + w4.z * p4.z + w4.w * p4.w;
        }
    }
    const float cb = conv_b[d];
#pragma unroll
    for (int t = 0; t < 16; ++t) {
        const float v = acc[t] + cb + pos[(size_t)pn[t] * Dm + d];
        H32[(size_t)(tok0 + t) * Dm + d] = v;
        H16[(size_t)(tok0 + t) * Dm + d] = f2bf(v);
    }
}

// --------------------- weight prep: f32 [K][N] -> bf16 [N][K] ---------------
__global__ __launch_bounds__(256) void k_wprep(const float* __restrict__ W,
                                               unsigned short* __restrict__ WT,
                                               int K, int N) {
    __shared__ float tile[64][65];
    const int layer = blockIdx.z;
    W  += (size_t)layer * K * N;
    WT += (size_t)layer * K * N;
    const int k0 = blockIdx.y * 64, n0 = blockIdx.x * 64;
    const int t = threadIdx.x;
#pragma unroll
    for (int it = 0; it < 4; ++it) {
        const int r = (t >> 4) + it * 16, c4 = (t & 15) * 4;
        *(float4*)&tile[r][c4] = *(const float4*)&W[(size_t)(k0 + r) * N + n0 + c4];
    }
    __syncthreads();
    const int n = t & 63, kq = t >> 6;
    unsigned short pk[16];
#pragma unroll
    for (int j = 0; j < 16; ++j) pk[j] = f2bf(tile[kq * 16 + j][n]);
    // R3 BUG WAS HERE: single uint4 store wrote only pk[0..7]. Write all 32B.
    unsigned short* dst = &WT[(size_t)(n0 + n) * K + k0 + kq * 16];
    *(uint4*)dst       = *(uint4*)&pk[0];
    *(uint4*)(dst + 8) = *(uint4*)&pk[8];
}

// ------------------------------ bf16 MFMA GEMM ------------------------------
// C[M,N] = A[M,K](bf16) @ W^T  (W given as [N][K] bf16)  + bias (+R) (ReLU)
// 128x128 tile, BK=64, 4 waves (2x2), global_load_lds w/ pre-swizzled source.
template <bool RELU, bool RES, bool OUT32, bool OUT16>
__global__ __launch_bounds__(256) void k_mgemm(const unsigned short* __restrict__ A,
                                               const unsigned short* __restrict__ W,
                                               const float* __restrict__ bias,
                                               const float* __restrict__ R,
                                               float* __restrict__ C32,
                                               unsigned short* __restrict__ C16,
                                               int M, int N, int K) {
    __shared__ unsigned short Al[128 * 64];
    __shared__ unsigned short Bl[128 * 64];
    const int tid = threadIdx.x;
    const int lane = tid & 63, wave = tid >> 6;
    const int wm = wave >> 1, wn = wave & 1;
    const int m0 = blockIdx.y * 128, n0 = blockIdx.x * 128;
    const int c = lane >> 4, a15 = lane & 15;
    f32x4 acc[4][4] = {};

    const int srow = lane >> 3;
    const int sgran = (lane & 7) ^ srow;   // pre-swizzled source granule

    for (int k0 = 0; k0 < K; k0 += 64) {
        __syncthreads();
#pragma unroll
        for (int q = 0; q < 4; ++q) {
            const int rbase = wave * 32 + q * 8;
            gload_lds16(A + (size_t)(m0 + rbase + srow) * K + k0 + sgran * 8,
                        &Al[rbase * 64]);
            gload_lds16(W + (size_t)(n0 + rbase + srow) * K + k0 + sgran * 8,
                        &Bl[rbase * 64]);
        }
        __syncthreads();
#pragma unroll
        for (int kc = 0; kc < 2; ++kc) {
            short8 af[4], bf[4];
#pragma unroll
            for (int fm = 0; fm < 4; ++fm) {
                const int row = wm * 64 + fm * 16 + a15;
                const int slot = (kc * 4 + c) ^ (row & 7);
                af[fm] = *(const short8*)&Al[row * 64 + slot * 8];
            }
#pragma unroll
            for (int fn = 0; fn < 4; ++fn) {
                const int row = wn * 64 + fn * 16 + a15;
                const int slot = (kc * 4 + c) ^ (row & 7);
                bf[fn] = *(const short8*)&Bl[row * 64 + slot * 8];
            }
#pragma unroll
            for (int fm = 0; fm < 4; ++fm)
#pragma unroll
                for (int fn = 0; fn < 4; ++fn)
                    acc[fm][fn] = __builtin_amdgcn_mfma_f32_16x16x32_bf16(
                        af[fm], bf[fn], acc[fm][fn], 0, 0, 0);
        }
    }
    // epilogue: D row = (lane>>4)*4 + reg (+fm*16), col = lane&15 (+fn*16)
#pragma unroll
    for (int fn = 0; fn < 4; ++fn) {
        const int col = n0 + wn * 64 + fn * 16 + a15;
        const float bv = bias[col];
#pragma unroll
        for (int fm = 0; fm < 4; ++fm) {
            const int mrow = m0 + wm * 64 + fm * 16 + c * 4;
#pragma unroll
            for (int r = 0; r < 4; ++r) {
                float v = acc[fm][fn][r] + bv;
                if constexpr (RES) v += R[(size_t)(mrow + r) * N + col];
                if constexpr (RELU) v = fmaxf(v, 0.f);
                if constexpr (OUT32) C32[(size_t)(mrow + r) * N + col] = v;
                if constexpr (OUT16) C16[(size_t)(mrow + r) * N + col] = f2bf(v);
            }
        }
    }
}

// ------------------------------- layernorm ---------------------------------
__global__ __launch_bounds__(256) void k_ln(const float* __restrict__ X,
                                            float* __restrict__ Y32,
                                            unsigned short* __restrict__ Y16,
                                            const float* __restrict__ s,
                                            const float* __restrict__ b) {
    const int row = blockIdx.x * 4 + (threadIdx.x >> 6);
    const int lane = threadIdx.x & 63;
    const float4 v = *(const float4*)&X[(size_t)row * Dm + lane * 4];
    float sum = v.x + v.y + v.z + v.w;
#pragma unroll
    for (int off = 32; off; off >>= 1) sum += __shfl_xor(sum, off);
    const float mean = sum * (1.f / 256.f);
    const float dx[4] = {v.x - mean, v.y - mean, v.z - mean, v.w - mean};
    float vv = dx[0] * dx[0] + dx[1] * dx[1] + dx[2] * dx[2] + dx[3] * dx[3];
#pragma unroll
    for (int off = 32; off; off >>= 1) vv += __shfl_xor(vv, off);
    const float inv = rsqrtf(vv * (1.f / 256.f) + 1e-5f);
    const float4 sv = *(const float4*)&s[lane * 4];
    const float4 bv = *(const float4*)&b[lane * 4];
    float o[4];
    o[0] = dx[0] * inv * sv.x + bv.x;
    o[1] = dx[1] * inv * sv.y + bv.y;
    o[2] = dx[2] * inv * sv.z + bv.z;
    o[3] = dx[3] * inv * sv.w + bv.w;
    *(float4*)&Y32[(size_t)row * Dm + lane * 4] = *(float4*)o;
    unsigned int pk[2];
    pk[0] = (unsigned int)f2bf(o[0]) | ((unsigned int)f2bf(o[1]) << 16);
    pk[1] = (unsigned int)f2bf(o[2]) | ((unsigned int)f2bf(o[3]) << 16);
    *(uint2*)&Y16[(size_t)row * Dm + lane * 4] = *(uint2*)pk;
}

// ------------------------- MFMA flash attention -----------------------------
// One block per (b,h). 512 thr = 8 waves, wave owns 64 q rows.
// Swapped QK^T: S^T[k][q] = mfma(A=K, B=Q) -> lane owns q = a15 (+fn*16),
// holds kv = c*4 + r (+fm*16) per 32-kv tile. Softmax reduce = shfl 16,32.
// P stays in registers as PV B-operand with sigma(c,j) = 4c+(j&3)+16*(j>>2),
// V^T supplied with the same sigma (permutation cancels).
__global__ __launch_bounds__(512) void k_attn(const unsigned short* __restrict__ QKV,
                                              unsigned short* __restrict__ O) {
    __shared__ unsigned short Kl[512 * 32];   // [k][d], XOR-swizzled 16B granules
    __shared__ unsigned short Vt[32 * 512];   // [d][k], XOR-swizzled 8B granules
    const int bh = blockIdx.x, b = bh >> 3, h = bh & 7;
    const int tid = threadIdx.x, lane = tid & 63, wave = tid >> 6;
    const int c = lane >> 4, a15 = lane & 15;
    const size_t qkvbase = (size_t)b * Lq * 768 + h * 32;

    // ---- stage K via global_load_lds (pre-swizzled source granules) ----
    {
        const int srow = lane >> 2;                        // 16 rows / 1KB chunk
        const int sg = (lane & 3) ^ ((srow >> 1) & 3);
#pragma unroll
        for (int q = 0; q < 4; ++q) {
            const int rbase = wave * 64 + q * 16;
            gload_lds16(QKV + qkvbase + (size_t)(rbase + srow) * 768 + 256 + sg * 8,
                        &Kl[rbase * 32]);
        }
    }
    // ---- stage V transposed: Vt[d][kv], granule(4 kv) at (kg ^ (d&7)) ----
    {
        const int kg = tid & 127, dg = tid >> 7;   // 4 kv rows, 8 d's each
        u32x4 v[4];
#pragma unroll
        for (int kk = 0; kk < 4; ++kk)
            v[kk] = *(const u32x4*)&QKV[qkvbase + (size_t)(kg * 4 + kk) * 768 + 512 + dg * 8];
#pragma unroll
        for (int dd = 0; dd < 8; ++dd) {
            const int d = dg * 8 + dd;
            unsigned short e[4];
#pragma unroll
            for (int kk = 0; kk < 4; ++kk) {
                const unsigned int word = v[kk][dd >> 1];
                e[kk] = (dd & 1) ? (unsigned short)(word >> 16) : (unsigned short)(word & 0xffff);
            }
            unsigned int pk[2];
            pk[0] = (unsigned int)e[0] | ((unsigned int)e[1] << 16);
            pk[1] = (unsigned int)e[2] | ((unsigned int)e[3] << 16);
            *(uint2*)&Vt[d * 512 + ((kg ^ (d & 7)) << 2)] = *(uint2*)pk;
        }
    }
    // ---- Q fragments (B-operand): Q[q0w+fn*16+a15][c*8+j] ----
    const int q0w = wave * 64;
    short8 qf[4];
#pragma unroll
    for (int fn = 0; fn < 4; ++fn)
        qf[fn] = *(const short8*)&QKV[qkvbase + (size_t)(q0w + fn * 16 + a15) * 768 + c * 8];
    __syncthreads();

    const float scale = 0.17677669529663687f;   // 1/sqrt(32)
    f32x4 oacc[2][4] = {};
    float mstat[4], lstat[4];
#pragma unroll
    for (int fn = 0; fn < 4; ++fn) { mstat[fn] = -1e30f; lstat[fn] = 0.f; }
    const f32x4 zero4 = {0.f, 0.f, 0.f, 0.f};

    for (int t = 0; t < 16; ++t) {
        const int kv0 = t * 32;
        short8 kf[2];
#pragma unroll
        for (int fm = 0; fm < 2; ++fm) {
            const int row = kv0 + fm * 16 + a15;
            const int slot = c ^ ((row >> 1) & 3);
            kf[fm] = *(const short8*)&Kl[row * 32 + slot * 8];
        }
        short8 vf[2];
#pragma unroll
        for (int fmd = 0; fmd < 2; ++fmd) {
            const int d = fmd * 16 + a15;
            const int g0 = (t * 8 + c) ^ (d & 7);
            const int g1 = (t * 8 + 4 + c) ^ (d & 7);
            const u32x2 r0 = *(const u32x2*)&Vt[d * 512 + g0 * 4];
            const u32x2 r1 = *(const u32x2*)&Vt[d * 512 + g1 * 4];
            const u32x4 cmb = {r0[0], r0[1], r1[0], r1[1]};
            vf[fmd] = __builtin_bit_cast(short8, cmb);
        }
        f32x4 s[2][4];
#pragma unroll
        for (int fm = 0; fm < 2; ++fm)
#pragma unroll
            for (int fn = 0; fn < 4; ++fn)
                s[fm][fn] = __builtin_amdgcn_mfma_f32_16x16x32_bf16(kf[fm], qf[fn], zero4, 0, 0, 0);
#pragma unroll
        for (int fn = 0; fn < 4; ++fn) {
            float p[8];
            float tmax = -1e30f;
#pragma unroll
            for (int fm = 0; fm < 2; ++fm)
#pragma unroll
                for (int r = 0; r < 4; ++r) {
                    const float x = s[fm][fn][r] * scale;
                    p[fm * 4 + r] = x;
                    tmax = fmaxf(tmax, x);
                }
            tmax = fmaxf(tmax, __shfl_xor(tmax, 16));
            tmax = fmaxf(tmax, __shfl_xor(tmax, 32));
            const float mnew = fmaxf(mstat[fn], tmax);
            const float alpha = __expf(mstat[fn] - mnew);
            mstat[fn] = mnew;
            float tsum = 0.f;
            short8 pf;
#pragma unroll
            for (int j = 0; j < 8; ++j) {
                const float e = __expf(p[j] - mnew);
                tsum += e;
                pf[j] = (short)f2bf(e);
            }
            tsum += __shfl_xor(tsum, 16);
            tsum += __shfl_xor(tsum, 32);
            lstat[fn] = lstat[fn] * alpha + tsum;
#pragma unroll
            for (int fmd = 0; fmd < 2; ++fmd) {
                oacc[fmd][fn] *= alpha;
                oacc[fmd][fn] = __builtin_amdgcn_mfma_f32_16x16x32_bf16(
                    vf[fmd], pf, oacc[fmd][fn], 0, 0, 0);
            }
        }
    }
#pragma unroll
    for (int fn = 0; fn < 4; ++fn) {
        const float invl = 1.f / lstat[fn];
        const size_t qrow = (size_t)(b * Lq + q0w + fn * 16 + a15);
#pragma unroll
        for (int fmd = 0; fmd < 2; ++fmd)
#pragma unroll
            for (int r = 0; r < 4; ++r)
                O[qrow * Dm + h * 32 + fmd * 16 + c * 4 + r] = f2bf(oacc[fmd][fn][r] * invl);
    }
}

// ------------------------------- launcher ----------------------------------
extern "C" void kernel_launch(void* const* d_in, const int* in_sizes, int n_in,
                              void* d_out, int out_size, void* d_ws, size_t ws_size,
                              hipStream_t stream) {
    const float* image  = (const float*)d_in[0];
    const float* mask   = (const float*)d_in[1];
    const float* conv_w = (const float*)d_in[2];
    const float* conv_b = (const float*)d_in[3];
    const float* pos    = (const float*)d_in[4];
    const float* qkv_w  = (const float*)d_in[5];
    const float* qkv_b  = (const float*)d_in[6];
    const float* out_w  = (const float*)d_in[7];
    const float* out_b  = (const float*)d_in[8];
    const float* ln1_s  = (const float*)d_in[9];
    const float* ln1_b  = (const float*)d_in[10];
    const float* ff1_w  = (const float*)d_in[11];
    const float* ff1_b  = (const float*)d_in[12];
    const float* ff2_w  = (const float*)d_in[13];
    const float* ff2_b  = (const float*)d_in[14];
    const float* ln2_s  = (const float*)d_in[15];
    const float* ln2_b  = (const float*)d_in[16];
    float* out = (float*)d_out;

    char* w = (char*)d_ws;
    int* order            = (int*)w;            w += 64 * 1024;
    float* H32            = (float*)w;          w += (size_t)Mtok * Dm * 4;
    unsigned short* H16   = (unsigned short*)w; w += (size_t)Mtok * Dm * 2;
    unsigned short* QKV16 = (unsigned short*)w; w += (size_t)Mtok * 768 * 2;
    unsigned short* O16   = (unsigned short*)w; w += (size_t)Mtok * Dm * 2;
    float* X32            = (float*)w;          w += (size_t)Mtok * Dm * 4;
    unsigned short* F16   = (unsigned short*)w; w += (size_t)Mtok * FFq * 2;
    unsigned short* Wq    = (unsigned short*)w; w += (size_t)4 * 768 * 256 * 2;
    unsigned short* Wo    = (unsigned short*)w; w += (size_t)4 * 256 * 256 * 2;
    unsigned short* Wf1   = (unsigned short*)w; w += (size_t)4 * 2048 * 256 * 2;
    unsigned short* Wf2   = (unsigned short*)w; w += (size_t)4 * 256 * 2048 * 2;

    k_order<<<Bq, 1024, 0, stream>>>(mask, order);
    k_embed<<<Mtok / 16, 256, 0, stream>>>(image, order, conv_w, conv_b, pos, H32, H16);

    k_wprep<<<dim3(12, 4, 4),  256, 0, stream>>>(qkv_w, Wq, 256, 768);
    k_wprep<<<dim3(4, 4, 4),   256, 0, stream>>>(out_w, Wo, 256, 256);
    k_wprep<<<dim3(32, 4, 4),  256, 0, stream>>>(ff1_w, Wf1, 256, 2048);
    k_wprep<<<dim3(4, 32, 4),  256, 0, stream>>>(ff2_w, Wf2, 2048, 256);

    for (int i = 0; i < 4; ++i) {
        k_mgemm<false, false, false, true><<<dim3(6, 128), 256, 0, stream>>>(
            H16, Wq + (size_t)i * 768 * 256, qkv_b + (size_t)i * 768, nullptr,
            nullptr, QKV16, Mtok, 768, 256);
        k_attn<<<Bq * Hh, 512, 0, stream>>>(QKV16, O16);
        k_mgemm<false, true, true, false><<<dim3(2, 128), 256, 0, stream>>>(
            O16, Wo + (size_t)i * 256 * 256, out_b + (size_t)i * 256, H32,
            X32, nullptr, Mtok, 256, 256);
        k_ln<<<Mtok / 4, 256, 0, stream>>>(X32, H32, H16, ln1_s + i * Dm, ln1_b + i * Dm);
        k_mgemm<true, false, false, true><<<dim3(16, 128), 256, 0, stream>>>(
            H16, Wf1 + (size_t)i * 2048 * 256, ff1_b + (size_t)i * FFq, nullptr,
            nullptr, F16, Mtok, 2048, 256);
        k_mgemm<false, true, true, false><<<dim3(2, 128), 256, 0, stream>>>(
            F16, Wf2 + (size_t)i * 256 * 2048, ff2_b + (size_t)i * 256, H32,
            X32, nullptr, Mtok, 256, 2048);
        float* dst32 = (i == 3) ? out : H32;
        k_ln<<<Mtok / 4, 256, 0, stream>>>(X32, dst32, H16, ln2_s + i * Dm, ln2_b + i * Dm);
    }
    (void)in_sizes; (void)n_in; (void)out_size; (void)ws_size;
}

// Round 5
// 694.418 us; speedup vs baseline: 31.2863x; 1.2741x over previous
//
#include <hip/hip_runtime.h>
#include <cstdint>
#include <cstddef>

// ---------------------------------------------------------------------------
// MaskedContextEncoder: B=32 IMG=512 P=16 CIN=4 D=256 DEPTH=4 H=8 FF=2048
// Round 5: MFMA-ize patch embed (R4 profile: k_embed 270us = 30% of total,
// VALU-bound fp32 GEMM). k_gather stages patches as bf16 [16384][768] +
// gathers pos rows; conv GEMM reuses k_mgemm (W = conv_w[:, :768] bf16,
// pos-add via residual path). patchA/posG alias the F16 region (dead before
// F16's first use). Everything else identical to R4.
// ---------------------------------------------------------------------------

#define Bq 32
#define Dm 256
#define Lq 512
#define Hh 8
#define FFq 2048
#define Mtok (Bq * Lq)   // 16384 rows

typedef __attribute__((ext_vector_type(8))) short  short8;
typedef __attribute__((ext_vector_type(4))) float  f32x4;
typedef __attribute__((ext_vector_type(4))) unsigned int u32x4;
typedef __attribute__((ext_vector_type(2))) unsigned int u32x2;

static __device__ __forceinline__ unsigned short f2bf(float f) {
    unsigned int u = __float_as_uint(f);
    unsigned int r = (u + 0x7FFFu + ((u >> 16) & 1u)) >> 16;
    return (unsigned short)r;
}
static __device__ __forceinline__ unsigned int pk2bf(float lo, float hi) {
    return (unsigned int)f2bf(lo) | ((unsigned int)f2bf(hi) << 16);
}

static __device__ __forceinline__ void gload_lds16(const void* g, void* l) {
    __builtin_amdgcn_global_load_lds(
        (const __attribute__((address_space(1))) unsigned int*)g,
        (__attribute__((address_space(3))) unsigned int*)l, 16, 0, 0);
}

// --------------------------- order (compaction) ----------------------------
__global__ __launch_bounds__(1024) void k_order(const float* __restrict__ mask,
                                                int* __restrict__ order) {
    const int b = blockIdx.x;
    const int n = threadIdx.x;
    const float v = mask[(size_t)b * 262144 + (size_t)(n >> 5) * 8192 + (n & 31) * 16];
    const bool sel = v < 0.5f;
    const unsigned long long ball = __ballot(sel);
    const int wave = n >> 6, lane = n & 63;
    __shared__ int wsum[16];
    __shared__ int wpre[16];
    if (lane == 0) wsum[wave] = __popcll(ball);
    __syncthreads();
    if (n == 0) {
        int s = 0;
        for (int i = 0; i < 16; ++i) { wpre[i] = s; s += wsum[i]; }
    }
    __syncthreads();
    const int rank = wpre[wave] + __popcll(ball & ((1ull << lane) - 1ull));
    if (sel) order[b * Lq + rank] = n;
}

// ----------------- gather: patches -> bf16 A, pos rows -> f32 ---------------
// Block = 256 thr, 16 tokens. patchA[m][c*256+rr*16+col] = image[b,c,...] bf16.
// posG[m][d] = pos[order[m]][d] f32.
__global__ __launch_bounds__(256) void k_gather(const float* __restrict__ image,
                                                const int* __restrict__ order,
                                                const float* __restrict__ pos,
                                                unsigned short* __restrict__ patchA,
                                                float* __restrict__ posG) {
    __shared__ int pn[16];
    const int tid = threadIdx.x;
    const int tok0 = blockIdx.x * 16;
    if (tid < 16) pn[tid] = order[tok0 + tid];
    __syncthreads();
    const int lane = tid & 63, w4 = tid >> 6;
    const int rr = lane >> 2, col4 = (lane & 3) << 2;
#pragma unroll
    for (int it = 0; it < 12; ++it) {
        const int s = it * 4 + w4;          // 0..47 slabs (t,c)
        const int t = s / 3, cch = s % 3;
        const int n = pn[t];
        const int b = (tok0 + t) >> 9;
        const int pi = n >> 5, pj = n & 31;
        const float4 v = *(const float4*)&image[
            (((size_t)b * 3 + cch) * 512 + pi * 16 + rr) * 512 + pj * 16 + col4];
        unsigned int pk[2] = {pk2bf(v.x, v.y), pk2bf(v.z, v.w)};
        *(uint2*)&patchA[(size_t)(tok0 + t) * 768 + cch * 256 + rr * 16 + col4] =
            *(uint2*)pk;
    }
#pragma unroll
    for (int it = 0; it < 4; ++it) {
        const int t = it * 4 + w4;
        *(float4*)&posG[(size_t)(tok0 + t) * Dm + lane * 4] =
            *(const float4*)&pos[(size_t)pn[t] * Dm + lane * 4];
    }
}

// ------------- conv weight: f32 [256][1024] -> bf16 [256][768] --------------
__global__ __launch_bounds__(256) void k_wembed(const float* __restrict__ conv_w,
                                                unsigned short* __restrict__ W16) {
    const int i = blockIdx.x * 256 + threadIdx.x;   // one uint4 out (8 elems)
    const int d = i / 96, k8 = (i % 96) * 8;        // 96 groups of 8 per row
    const float4 a = *(const float4*)&conv_w[(size_t)d * 1024 + k8];
    const float4 b = *(const float4*)&conv_w[(size_t)d * 1024 + k8 + 4];
    unsigned int pk[4] = {pk2bf(a.x, a.y), pk2bf(a.z, a.w),
                          pk2bf(b.x, b.y), pk2bf(b.z, b.w)};
    *(uint4*)&W16[(size_t)d * 768 + k8] = *(uint4*)pk;
}

// --------------------- weight prep: f32 [K][N] -> bf16 [N][K] ---------------
__global__ __launch_bounds__(256) void k_wprep(const float* __restrict__ W,
                                               unsigned short* __restrict__ WT,
                                               int K, int N) {
    __shared__ float tile[64][65];
    const int layer = blockIdx.z;
    W  += (size_t)layer * K * N;
    WT += (size_t)layer * K * N;
    const int k0 = blockIdx.y * 64, n0 = blockIdx.x * 64;
    const int t = threadIdx.x;
#pragma unroll
    for (int it = 0; it < 4; ++it) {
        const int r = (t >> 4) + it * 16, c4 = (t & 15) * 4;
        *(float4*)&tile[r][c4] = *(const float4*)&W[(size_t)(k0 + r) * N + n0 + c4];
    }
    __syncthreads();
    const int n = t & 63, kq = t >> 6;
    unsigned short pk[16];
#pragma unroll
    for (int j = 0; j < 16; ++j) pk[j] = f2bf(tile[kq * 16 + j][n]);
    unsigned short* dst = &WT[(size_t)(n0 + n) * K + k0 + kq * 16];
    *(uint4*)dst       = *(uint4*)&pk[0];
    *(uint4*)(dst + 8) = *(uint4*)&pk[8];
}

// ------------------------------ bf16 MFMA GEMM ------------------------------
// C[M,N] = A[M,K](bf16) @ W^T (W as [N][K] bf16) + bias (+R) (ReLU).
// 128x128 tile, BK=64, 4 waves (2x2), global_load_lds w/ pre-swizzled source.
template <bool RELU, bool RES, bool OUT32, bool OUT16>
__global__ __launch_bounds__(256) void k_mgemm(const unsigned short* __restrict__ A,
                                               const unsigned short* __restrict__ W,
                                               const float* __restrict__ bias,
                                               const float* __restrict__ R,
                                               float* __restrict__ C32,
                                               unsigned short* __restrict__ C16,
                                               int M, int N, int K) {
    __shared__ unsigned short Al[128 * 64];
    __shared__ unsigned short Bl[128 * 64];
    const int tid = threadIdx.x;
    const int lane = tid & 63, wave = tid >> 6;
    const int wm = wave >> 1, wn = wave & 1;
    const int m0 = blockIdx.y * 128, n0 = blockIdx.x * 128;
    const int c = lane >> 4, a15 = lane & 15;
    f32x4 acc[4][4] = {};

    const int srow = lane >> 3;
    const int sgran = (lane & 7) ^ srow;   // pre-swizzled source granule

    for (int k0 = 0; k0 < K; k0 += 64) {
        __syncthreads();
#pragma unroll
        for (int q = 0; q < 4; ++q) {
            const int rbase = wave * 32 + q * 8;
            gload_lds16(A + (size_t)(m0 + rbase + srow) * K + k0 + sgran * 8,
                        &Al[rbase * 64]);
            gload_lds16(W + (size_t)(n0 + rbase + srow) * K + k0 + sgran * 8,
                        &Bl[rbase * 64]);
        }
        __syncthreads();
#pragma unroll
        for (int kc = 0; kc < 2; ++kc) {
            short8 af[4], bf[4];
#pragma unroll
            for (int fm = 0; fm < 4; ++fm) {
                const int row = wm * 64 + fm * 16 + a15;
                const int slot = (kc * 4 + c) ^ (row & 7);
                af[fm] = *(const short8*)&Al[row * 64 + slot * 8];
            }
#pragma unroll
            for (int fn = 0; fn < 4; ++fn) {
                const int row = wn * 64 + fn * 16 + a15;
                const int slot = (kc * 4 + c) ^ (row & 7);
                bf[fn] = *(const short8*)&Bl[row * 64 + slot * 8];
            }
#pragma unroll
            for (int fm = 0; fm < 4; ++fm)
#pragma unroll
                for (int fn = 0; fn < 4; ++fn)
                    acc[fm][fn] = __builtin_amdgcn_mfma_f32_16x16x32_bf16(
                        af[fm], bf[fn], acc[fm][fn], 0, 0, 0);
        }
    }
#pragma unroll
    for (int fn = 0; fn < 4; ++fn) {
        const int col = n0 + wn * 64 + fn * 16 + a15;
        const float bv = bias[col];
#pragma unroll
        for (int fm = 0; fm < 4; ++fm) {
            const int mrow = m0 + wm * 64 + fm * 16 + c * 4;
#pragma unroll
            for (int r = 0; r < 4; ++r) {
                float v = acc[fm][fn][r] + bv;
                if constexpr (RES) v += R[(size_t)(mrow + r) * N + col];
                if constexpr (RELU) v = fmaxf(v, 0.f);
                if constexpr (OUT32) C32[(size_t)(mrow + r) * N + col] = v;
                if constexpr (OUT16) C16[(size_t)(mrow + r) * N + col] = f2bf(v);
            }
        }
    }
}

// ------------------------------- layernorm ---------------------------------
__global__ __launch_bounds__(256) void k_ln(const float* __restrict__ X,
                                            float* __restrict__ Y32,
                                            unsigned short* __restrict__ Y16,
                                            const float* __restrict__ s,
                                            const float* __restrict__ b) {
    const int row = blockIdx.x * 4 + (threadIdx.x >> 6);
    const int lane = threadIdx.x & 63;
    const float4 v = *(const float4*)&X[(size_t)row * Dm + lane * 4];
    float sum = v.x + v.y + v.z + v.w;
#pragma unroll
    for (int off = 32; off; off >>= 1) sum += __shfl_xor(sum, off);
    const float mean = sum * (1.f / 256.f);
    const float dx[4] = {v.x - mean, v.y - mean, v.z - mean, v.w - mean};
    float vv = dx[0] * dx[0] + dx[1] * dx[1] + dx[2] * dx[2] + dx[3] * dx[3];
#pragma unroll
    for (int off = 32; off; off >>= 1) vv += __shfl_xor(vv, off);
    const float inv = rsqrtf(vv * (1.f / 256.f) + 1e-5f);
    const float4 sv = *(const float4*)&s[lane * 4];
    const float4 bv = *(const float4*)&b[lane * 4];
    float o[4];
    o[0] = dx[0] * inv * sv.x + bv.x;
    o[1] = dx[1] * inv * sv.y + bv.y;
    o[2] = dx[2] * inv * sv.z + bv.z;
    o[3] = dx[3] * inv * sv.w + bv.w;
    *(float4*)&Y32[(size_t)row * Dm + lane * 4] = *(float4*)o;
    unsigned int pk[2] = {pk2bf(o[0], o[1]), pk2bf(o[2], o[3])};
    *(uint2*)&Y16[(size_t)row * Dm + lane * 4] = *(uint2*)pk;
}

// ------------------------- MFMA flash attention -----------------------------
__global__ __launch_bounds__(512) void k_attn(const unsigned short* __restrict__ QKV,
                                              unsigned short* __restrict__ O) {
    __shared__ unsigned short Kl[512 * 32];   // [k][d], XOR-swizzled 16B granules
    __shared__ unsigned short Vt[32 * 512];   // [d][k], XOR-swizzled 8B granules
    const int bh = blockIdx.x, b = bh >> 3, h = bh & 7;
    const int tid = threadIdx.x, lane = tid & 63, wave = tid >> 6;
    const int c = lane >> 4, a15 = lane & 15;
    const size_t qkvbase = (size_t)b * Lq * 768 + h * 32;

    {
        const int srow = lane >> 2;
        const int sg = (lane & 3) ^ ((srow >> 1) & 3);
#pragma unroll
        for (int q = 0; q < 4; ++q) {
            const int rbase = wave * 64 + q * 16;
            gload_lds16(QKV + qkvbase + (size_t)(rbase + srow) * 768 + 256 + sg * 8,
                        &Kl[rbase * 32]);
        }
    }
    {
        const int kg = tid & 127, dg = tid >> 7;
        u32x4 v[4];
#pragma unroll
        for (int kk = 0; kk < 4; ++kk)
            v[kk] = *(const u32x4*)&QKV[qkvbase + (size_t)(kg * 4 + kk) * 768 + 512 + dg * 8];
#pragma unroll
        for (int dd = 0; dd < 8; ++dd) {
            const int d = dg * 8 + dd;
            unsigned short e[4];
#pragma unroll
            for (int kk = 0; kk < 4; ++kk) {
                const unsigned int word = v[kk][dd >> 1];
                e[kk] = (dd & 1) ? (unsigned short)(word >> 16) : (unsigned short)(word & 0xffff);
            }
            unsigned int pk[2];
            pk[0] = (unsigned int)e[0] | ((unsigned int)e[1] << 16);
            pk[1] = (unsigned int)e[2] | ((unsigned int)e[3] << 16);
            *(uint2*)&Vt[d * 512 + ((kg ^ (d & 7)) << 2)] = *(uint2*)pk;
        }
    }
    const int q0w = wave * 64;
    short8 qf[4];
#pragma unroll
    for (int fn = 0; fn < 4; ++fn)
        qf[fn] = *(const short8*)&QKV[qkvbase + (size_t)(q0w + fn * 16 + a15) * 768 + c * 8];
    __syncthreads();

    const float scale = 0.17677669529663687f;   // 1/sqrt(32)
    f32x4 oacc[2][4] = {};
    float mstat[4], lstat[4];
#pragma unroll
    for (int fn = 0; fn < 4; ++fn) { mstat[fn] = -1e30f; lstat[fn] = 0.f; }
    const f32x4 zero4 = {0.f, 0.f, 0.f, 0.f};

    for (int t = 0; t < 16; ++t) {
        const int kv0 = t * 32;
        short8 kf[2];
#pragma unroll
        for (int fm = 0; fm < 2; ++fm) {
            const int row = kv0 + fm * 16 + a15;
            const int slot = c ^ ((row >> 1) & 3);
            kf[fm] = *(const short8*)&Kl[row * 32 + slot * 8];
        }
        short8 vf[2];
#pragma unroll
        for (int fmd = 0; fmd < 2; ++fmd) {
            const int d = fmd * 16 + a15;
            const int g0 = (t * 8 + c) ^ (d & 7);
            const int g1 = (t * 8 + 4 + c) ^ (d & 7);
            const u32x2 r0 = *(const u32x2*)&Vt[d * 512 + g0 * 4];
            const u32x2 r1 = *(const u32x2*)&Vt[d * 512 + g1 * 4];
            const u32x4 cmb = {r0[0], r0[1], r1[0], r1[1]};
            vf[fmd] = __builtin_bit_cast(short8, cmb);
        }
        f32x4 s[2][4];
#pragma unroll
        for (int fm = 0; fm < 2; ++fm)
#pragma unroll
            for (int fn = 0; fn < 4; ++fn)
                s[fm][fn] = __builtin_amdgcn_mfma_f32_16x16x32_bf16(kf[fm], qf[fn], zero4, 0, 0, 0);
#pragma unroll
        for (int fn = 0; fn < 4; ++fn) {
            float p[8];
            float tmax = -1e30f;
#pragma unroll
            for (int fm = 0; fm < 2; ++fm)
#pragma unroll
                for (int r = 0; r < 4; ++r) {
                    const float x = s[fm][fn][r] * scale;
                    p[fm * 4 + r] = x;
                    tmax = fmaxf(tmax, x);
                }
            tmax = fmaxf(tmax, __shfl_xor(tmax, 16));
            tmax = fmaxf(tmax, __shfl_xor(tmax, 32));
            const float mnew = fmaxf(mstat[fn], tmax);
            const float alpha = __expf(mstat[fn] - mnew);
            mstat[fn] = mnew;
            float tsum = 0.f;
            short8 pf;
#pragma unroll
            for (int j = 0; j < 8; ++j) {
                const float e = __expf(p[j] - mnew);
                tsum += e;
                pf[j] = (short)f2bf(e);
            }
            tsum += __shfl_xor(tsum, 16);
            tsum += __shfl_xor(tsum, 32);
            lstat[fn] = lstat[fn] * alpha + tsum;
#pragma unroll
            for (int fmd = 0; fmd < 2; ++fmd) {
                oacc[fmd][fn] *= alpha;
                oacc[fmd][fn] = __builtin_amdgcn_mfma_f32_16x16x32_bf16(
                    vf[fmd], pf, oacc[fmd][fn], 0, 0, 0);
            }
        }
    }
#pragma unroll
    for (int fn = 0; fn < 4; ++fn) {
        const float invl = 1.f / lstat[fn];
        const size_t qrow = (size_t)(b * Lq + q0w + fn * 16 + a15);
#pragma unroll
        for (int fmd = 0; fmd < 2; ++fmd)
#pragma unroll
            for (int r = 0; r < 4; ++r)
                O[qrow * Dm + h * 32 + fmd * 16 + c * 4 + r] = f2bf(oacc[fmd][fn][r] * invl);
    }
}

// ------------------------------- launcher ----------------------------------
extern "C" void kernel_launch(void* const* d_in, const int* in_sizes, int n_in,
                              void* d_out, int out_size, void* d_ws, size_t ws_size,
                              hipStream_t stream) {
    const float* image  = (const float*)d_in[0];
    const float* mask   = (const float*)d_in[1];
    const float* conv_w = (const float*)d_in[2];
    const float* conv_b = (const float*)d_in[3];
    const float* pos    = (const float*)d_in[4];
    const float* qkv_w  = (const float*)d_in[5];
    const float* qkv_b  = (const float*)d_in[6];
    const float* out_w  = (const float*)d_in[7];
    const float* out_b  = (const float*)d_in[8];
    const float* ln1_s  = (const float*)d_in[9];
    const float* ln1_b  = (const float*)d_in[10];
    const float* ff1_w  = (const float*)d_in[11];
    const float* ff1_b  = (const float*)d_in[12];
    const float* ff2_w  = (const float*)d_in[13];
    const float* ff2_b  = (const float*)d_in[14];
    const float* ln2_s  = (const float*)d_in[15];
    const float* ln2_b  = (const float*)d_in[16];
    float* out = (float*)d_out;

    char* w = (char*)d_ws;
    int* order            = (int*)w;            w += 64 * 1024;
    float* H32            = (float*)w;          w += (size_t)Mtok * Dm * 4;
    unsigned short* H16   = (unsigned short*)w; w += (size_t)Mtok * Dm * 2;
    unsigned short* QKV16 = (unsigned short*)w; w += (size_t)Mtok * 768 * 2;
    unsigned short* O16   = (unsigned short*)w; w += (size_t)Mtok * Dm * 2;
    float* X32            = (float*)w;          w += (size_t)Mtok * Dm * 4;
    unsigned short* F16   = (unsigned short*)w; w += (size_t)Mtok * FFq * 2;
    unsigned short* Wq    = (unsigned short*)w; w += (size_t)4 * 768 * 256 * 2;
    unsigned short* Wo    = (unsigned short*)w; w += (size_t)4 * 256 * 256 * 2;
    unsigned short* Wf1   = (unsigned short*)w; w += (size_t)4 * 2048 * 256 * 2;
    unsigned short* Wf2   = (unsigned short*)w; w += (size_t)4 * 256 * 2048 * 2;
    unsigned short* We    = (unsigned short*)w; w += (size_t)256 * 768 * 2;
    // embed-only buffers alias F16 (42 MB < 67 MB; dead before F16 written)
    unsigned short* patchA = F16;
    float* posG            = (float*)(F16 + (size_t)Mtok * 768);

    k_order<<<Bq, 1024, 0, stream>>>(mask, order);
    k_gather<<<Mtok / 16, 256, 0, stream>>>(image, order, pos, patchA, posG);
    k_wembed<<<96, 256, 0, stream>>>(conv_w, We);
    k_wprep<<<dim3(12, 4, 4),  256, 0, stream>>>(qkv_w, Wq, 256, 768);
    k_wprep<<<dim3(4, 4, 4),   256, 0, stream>>>(out_w, Wo, 256, 256);
    k_wprep<<<dim3(32, 4, 4),  256, 0, stream>>>(ff1_w, Wf1, 256, 2048);
    k_wprep<<<dim3(4, 32, 4),  256, 0, stream>>>(ff2_w, Wf2, 2048, 256);

    // patch-embed GEMM: [16384,768] @ We^T + conv_b + posG -> H32, H16
    k_mgemm<false, true, true, true><<<dim3(2, 128), 256, 0, stream>>>(
        patchA, We, conv_b, posG, H32, H16, Mtok, 256, 768);

    for (int i = 0; i < 4; ++i) {
        k_mgemm<false, false, false, true><<<dim3(6, 128), 256, 0, stream>>>(
            H16, Wq + (size_t)i * 768 * 256, qkv_b + (size_t)i * 768, nullptr,
            nullptr, QKV16, Mtok, 768, 256);
        k_attn<<<Bq * Hh, 512, 0, stream>>>(QKV16, O16);
        k_mgemm<false, true, true, false><<<dim3(2, 128), 256, 0, stream>>>(
            O16, Wo + (size_t)i * 256 * 256, out_b + (size_t)i * 256, H32,
            X32, nullptr, Mtok, 256, 256);
        k_ln<<<Mtok / 4, 256, 0, stream>>>(X32, H32, H16, ln1_s + i * Dm, ln1_b + i * Dm);
        k_mgemm<true, false, false, true><<<dim3(16, 128), 256, 0, stream>>>(
            H16, Wf1 + (size_t)i * 2048 * 256, ff1_b + (size_t)i * FFq, nullptr,
            nullptr, F16, Mtok, 2048, 256);
        k_mgemm<false, true, true, false><<<dim3(2, 128), 256, 0, stream>>>(
            F16, Wf2 + (size_t)i * 256 * 2048, ff2_b + (size_t)i * 256, H32,
            X32, nullptr, Mtok, 256, 2048);
        float* dst32 = (i == 3) ? out : H32;
        k_ln<<<Mtok / 4, 256, 0, stream>>>(X32, dst32, H16, ln2_s + i * Dm, ln2_b + i * Dm);
    }
    (void)in_sizes; (void)n_in; (void)out_size; (void)ws_size;
}